// Round 12
// baseline (2006.954 us; speedup 1.0000x reference)
//
#include <hip/hip_runtime.h>
#include <math.h>

#define NN 20000
#define EE 320000
#define BN_SC 0.9999950000374997f

typedef __attribute__((ext_vector_type(8))) short bf16x8;
typedef __attribute__((ext_vector_type(4))) float f32x4;

__device__ __forceinline__ unsigned short f2b(float x) {
  unsigned int u = __builtin_bit_cast(unsigned int, x);
  u += 0x7FFFu + ((u >> 16) & 1u);
  return (unsigned short)(u >> 16);
}
__device__ __forceinline__ void split2(float x, unsigned short& h, unsigned short& l) {
  h = f2b(x);
  float hf = __builtin_bit_cast(float, (unsigned int)h << 16);
  l = f2b(x - hf);
}

// paired split via v_cvt_pk_bf16_f32 (1 instr converts 2 f32->2 bf16, RNE):
// ~4 VALU ops/value vs split2's ~12 — the R12 profile showed VALUBusy 46.7%
// nearly matching MfmaUtil, with split2 epilogues the main VALU consumer.
__device__ __forceinline__ unsigned int cvtpk(float a, float b) {
  unsigned int r;
  asm("v_cvt_pk_bf16_f32 %0, %1, %2" : "=v"(r) : "v"(a), "v"(b));
  return r;
}
__device__ __forceinline__ void split_pair(float x0, float x1, unsigned int& hp, unsigned int& lp) {
  hp = cvtpk(x0, x1);
  float h0 = __builtin_bit_cast(float, hp << 16);
  float h1 = __builtin_bit_cast(float, hp & 0xFFFF0000u);
  lp = cvtpk(x0 - h0, x1 - h1);
}

// ======================= weight split + MFMA-fragment repack =======================
__global__ __launch_bounds__(256) void k_wpack(const float* __restrict__ W, unsigned short* __restrict__ Wh,
                                               unsigned short* __restrict__ Wl, int C, int K) {
  int i = blockIdx.x * 256 + threadIdx.x;
  if (i >= C * K) return;
  int e = i & 7;
  int lane = (i >> 3) & 63;
  int tile = i >> 9;
  int KT = K >> 5;
  int kt = tile % KT, ct = tile / KT;
  int lr = lane & 15, lg = lane >> 4;
  int col = ct * 16 + lr;
  int k = kt * 32 + lg * 8 + e;
  unsigned short h, l;
  split2(W[(size_t)col * K + k], h, l);
  Wh[i] = h;
  Wl[i] = l;
}

// ======================= CSR build (by destination col) =======================
__global__ __launch_bounds__(256) void k_count(const int* __restrict__ colv, int* __restrict__ cnt) {
  int e = blockIdx.x * 256 + threadIdx.x;
  if (e < EE) atomicAdd(&cnt[colv[e]], 1);
}

// hierarchical scan (R12's single-block 200-barrier scan was ~30-60us)
__global__ __launch_bounds__(256) void k_scan1(const int* __restrict__ cnt, int* __restrict__ offs,
                                               int* __restrict__ bsum) {
  __shared__ int sb[256];
  int t = threadIdx.x, i = blockIdx.x * 256 + t;
  int v = (i < NN) ? cnt[i] : 0;
  sb[t] = v;
  __syncthreads();
  for (int off = 1; off < 256; off <<= 1) {
    int x = (t >= off) ? sb[t - off] : 0;
    __syncthreads();
    sb[t] += x;
    __syncthreads();
  }
  if (i < NN) offs[i + 1] = sb[t];  // block-inclusive
  if (t == 255) bsum[blockIdx.x] = sb[255];
}
__global__ __launch_bounds__(128) void k_scan2(int* __restrict__ bsum) {
  __shared__ int sb[128];
  int t = threadIdx.x;
  int v = (t < 79) ? bsum[t] : 0;
  sb[t] = v;
  __syncthreads();
  for (int off = 1; off < 128; off <<= 1) {
    int x = (t >= off) ? sb[t - off] : 0;
    __syncthreads();
    sb[t] += x;
    __syncthreads();
  }
  if (t < 79) bsum[t] = sb[t] - v;  // exclusive
}
__global__ __launch_bounds__(256) void k_scan3(const int* __restrict__ bsum, int* __restrict__ offs) {
  int i = blockIdx.x * 256 + threadIdx.x;
  if (i == 0) offs[0] = 0;
  if (i < NN) offs[i + 1] += bsum[blockIdx.x];
}

__global__ __launch_bounds__(256) void k_fill(const int* __restrict__ colv, const int* __restrict__ offs,
                                              int* __restrict__ cur, int* __restrict__ eid) {
  int e = blockIdx.x * 256 + threadIdx.x;
  if (e < EE) {
    int d = colv[e];
    int p = atomicAdd(&cur[d], 1);
    eid[offs[d] + p] = e;
  }
}

// deterministic per-node edge order; sort in LDS (R12 sorted in GLOBAL memory:
// serial dependent ~500-cyc round-trips, worst-degree nodes ~800 iters -> 100-200us)
__global__ __launch_bounds__(64) void k_sortl(const int* __restrict__ offs, int* __restrict__ eid) {
  __shared__ int buf[64 * 97];  // 97 stride: avoid 64-way bank conflict (96%32==0)
  int n = blockIdx.x * 64 + threadIdx.x;
  if (n >= NN) return;
  int j0 = offs[n], j1 = offs[n + 1], d = j1 - j0;
  int* b = &buf[threadIdx.x * 97];
  if (d <= 96) {
    for (int i = 0; i < d; ++i) b[i] = eid[j0 + i];
    for (int i = 1; i < d; ++i) {
      int v = b[i];
      int j = i - 1;
      while (j >= 0 && b[j] > v) { b[j + 1] = b[j]; --j; }
      b[j + 1] = v;
    }
    for (int i = 0; i < d; ++i) eid[j0 + i] = b[i];
  } else {
    for (int i = j0 + 1; i < j1; ++i) {
      int v = eid[i];
      int j = i - 1;
      while (j >= j0 && eid[j] > v) { eid[j + 1] = eid[j]; --j; }
      eid[j + 1] = v;
    }
  }
}

// pack (weight, src_row) per CSR slot; lapw computed inline
__global__ __launch_bounds__(256) void k_pack(const int* __restrict__ eid, const int* __restrict__ rowi,
                                              const int* __restrict__ colv,
                                              const float* __restrict__ ew, const float* __restrict__ dinv,
                                              float2* __restrict__ packW, float2* __restrict__ packL) {
  int j = blockIdx.x * 256 + threadIdx.x;
  if (j < EE) {
    int e = eid[j];
    int r = rowi[e], c = colv[e];
    float rw = __int_as_float(r);
    float w = (r == c) ? 0.f : ew[e];
    packW[j] = make_float2(ew[e], rw);
    packL[j] = make_float2(-dinv[r] * w * dinv[c], rw);
  }
}

// ======================= fused edge MLP (MFMA split-bf16) + cosine =======================
// 32 edges (64 rows)/block, 512 threads = 8 waves, 48 KB LDS, 2 blocks/CU.
// Structure = R12 (fragment-packed weights, H1 dbuf, 1 barrier/kc, R8 register envelope).
// R13: cvt_pk split pairs + vectorized X-staging LDS writes (VALU cut).
#define MFMA16(a, b, c) __builtin_amdgcn_mfma_f32_16x16x32_bf16(a, b, c, 0, 0, 0)

__global__ __launch_bounds__(512, 2) void k_edge_mlp(
    const float* __restrict__ X,
    const unsigned short* __restrict__ W1h, const unsigned short* __restrict__ W1l, const float* __restrict__ b1,
    const unsigned short* __restrict__ W2h, const unsigned short* __restrict__ W2l, const float* __restrict__ b2,
    const unsigned short* __restrict__ W3h, const unsigned short* __restrict__ W3l, const float* __restrict__ b3,
    float* __restrict__ ew) {
  __shared__ __align__(16) unsigned short POOL[24576];  // 48 KB
  unsigned short* Xh = POOL;          // [64][64]
  unsigned short* Xl = POOL + 4096;   // [64][64]
  unsigned short* H2ch = POOL + 8192;   // phase C: [64][128], aliases H1 bufs
  unsigned short* H2cl = POOL + 16384;  // phase C: [64][128]
  float* H3 = (float*)(POOL + 8192);    // tail: [64][128] f32 = 32KB

  const int tid = threadIdx.x;
  const int wv = tid >> 6;
  const int lane = tid & 63;
  const int lr = lane & 15;
  const int lg = lane >> 4;
  const int e0 = blockIdx.x * 32;
  const int lane8 = lane << 3;

  const int rt1 = wv & 3;
  const int ch1 = wv >> 2;

  // ---- stage X[64 rows][64 cols] as split bf16, swizzled; one 16B write/plane ----
  {
    int row = tid >> 3, eighth = tid & 7;
    const float* src = X + (size_t)(e0 + (row >> 1)) * 128 + (row & 1) * 64 + eighth * 8;
    float4 a = ((const float4*)src)[0];
    float4 b = ((const float4*)src)[1];
    float vals[8] = {a.x, a.y, a.z, a.w, b.x, b.y, b.z, b.w};
    unsigned int hp[4], lp[4];
#pragma unroll
    for (int p = 0; p < 4; ++p) split_pair(vals[2 * p], vals[2 * p + 1], hp[p], lp[p]);
    int chunk = eighth ^ (row & 7);
    int idxs = row * 64 + chunk * 8;
    *(uint4*)&Xh[idxs] = make_uint4(hp[0], hp[1], hp[2], hp[3]);
    *(uint4*)&Xl[idxs] = make_uint4(lp[0], lp[1], lp[2], lp[3]);
  }
  __syncthreads();

  // layer-1 compute for 64-col chunk c into H1 buffer b.
  auto l1_compute = [&](int c, int b) {
    unsigned short* H1h = POOL + 8192 + b * 8192;
    unsigned short* H1l = POOL + 12288 + b * 8192;
    f32x4 acc1[2];
#pragma unroll
    for (int cti = 0; cti < 2; ++cti) acc1[cti] = f32x4{0.f, 0.f, 0.f, 0.f};
#pragma unroll
    for (int kt = 0; kt < 2; ++kt) {
      int arow = 16 * rt1 + lr;
      int aidx = arow * 64 + ((4 * kt + lg) ^ (arow & 7)) * 8;
      bf16x8 ah = *(const bf16x8*)&Xh[aidx];
      bf16x8 al = *(const bf16x8*)&Xl[aidx];
#pragma unroll
      for (int cti = 0; cti < 2; ++cti) {
        int off = (((4 * c + 2 * ch1 + cti) * 2 + kt) << 9) + lane8;
        bf16x8 bh = *(const bf16x8*)(W1h + off);
        bf16x8 bl = *(const bf16x8*)(W1l + off);
        acc1[cti] = MFMA16(ah, bh, acc1[cti]);
        acc1[cti] = MFMA16(ah, bl, acc1[cti]);
        acc1[cti] = MFMA16(al, bh, acc1[cti]);
      }
    }
#pragma unroll
    for (int cti = 0; cti < 2; ++cti) {
      int colL = 16 * (2 * ch1 + cti) + lr;
      float bias = b1[64 * c + colL];
      float vv[4];
#pragma unroll
      for (int r = 0; r < 4; ++r) vv[r] = fmaxf(acc1[cti][r] + bias, 0.f) * BN_SC;
      unsigned int hp0, lp0, hp1, lp1;
      split_pair(vv[0], vv[1], hp0, lp0);
      split_pair(vv[2], vv[3], hp1, lp1);
      unsigned short hs[4] = {(unsigned short)hp0, (unsigned short)(hp0 >> 16),
                              (unsigned short)hp1, (unsigned short)(hp1 >> 16)};
      unsigned short ls[4] = {(unsigned short)lp0, (unsigned short)(lp0 >> 16),
                              (unsigned short)lp1, (unsigned short)(lp1 >> 16)};
#pragma unroll
      for (int r = 0; r < 4; ++r) {
        int row = 16 * rt1 + 4 * lg + r;
        int idxs = row * 64 + (((colL >> 3) ^ (row & 7)) * 8) + (colL & 7);
        H1h[idxs] = hs[r];
        H1l[idxs] = ls[r];
      }
    }
  };

  f32x4 acc2[4][2];
#pragma unroll
  for (int rt = 0; rt < 4; ++rt)
#pragma unroll
    for (int ct = 0; ct < 2; ++ct) acc2[rt][ct] = f32x4{0.f, 0.f, 0.f, 0.f};

  l1_compute(0, 0);
  __syncthreads();

  // ===== pipelined main loop: 8 chunks of 64 H1-cols, ONE barrier each =====
  for (int kc = 0; kc < 8; ++kc) {
    int cur = kc & 1;
    unsigned short* H1h = POOL + 8192 + cur * 8192;
    unsigned short* H1l = POOL + 12288 + cur * 8192;
    bf16x8 p2h[2], p2l[2];
    {
#pragma unroll
      for (int ct = 0; ct < 2; ++ct) {
        int off = (((8 * ct + wv) * 16 + 2 * kc) << 9) + lane8;
        p2h[ct] = *(const bf16x8*)(W2h + off);
        p2l[ct] = *(const bf16x8*)(W2l + off);
      }
    }
    if (kc < 7) l1_compute(kc + 1, cur ^ 1);
    bf16x8 q2h[2], q2l[2];
    {
#pragma unroll
      for (int ct = 0; ct < 2; ++ct) {
        int off = (((8 * ct + wv) * 16 + 2 * kc + 1) << 9) + lane8;
        q2h[ct] = *(const bf16x8*)(W2h + off);
        q2l[ct] = *(const bf16x8*)(W2l + off);
      }
    }
#pragma unroll
    for (int rtg = 0; rtg < 2; ++rtg) {
      bf16x8 ah[2], al[2];
#pragma unroll
      for (int rti = 0; rti < 2; ++rti) {
        int arow = 32 * rtg + 16 * rti + lr;
        int aidx = arow * 64 + (lg ^ (arow & 7)) * 8;
        ah[rti] = *(const bf16x8*)&H1h[aidx];
        al[rti] = *(const bf16x8*)&H1l[aidx];
      }
#pragma unroll
      for (int ct = 0; ct < 2; ++ct)
#pragma unroll
        for (int rti = 0; rti < 2; ++rti) {
          acc2[2 * rtg + rti][ct] = MFMA16(ah[rti], p2h[ct], acc2[2 * rtg + rti][ct]);
          acc2[2 * rtg + rti][ct] = MFMA16(ah[rti], p2l[ct], acc2[2 * rtg + rti][ct]);
          acc2[2 * rtg + rti][ct] = MFMA16(al[rti], p2h[ct], acc2[2 * rtg + rti][ct]);
        }
    }
#pragma unroll
    for (int rtg = 0; rtg < 2; ++rtg) {
      bf16x8 ah[2], al[2];
#pragma unroll
      for (int rti = 0; rti < 2; ++rti) {
        int arow = 32 * rtg + 16 * rti + lr;
        int aidx = arow * 64 + ((4 + lg) ^ (arow & 7)) * 8;
        ah[rti] = *(const bf16x8*)&H1h[aidx];
        al[rti] = *(const bf16x8*)&H1l[aidx];
      }
#pragma unroll
      for (int ct = 0; ct < 2; ++ct)
#pragma unroll
        for (int rti = 0; rti < 2; ++rti) {
          acc2[2 * rtg + rti][ct] = MFMA16(ah[rti], q2h[ct], acc2[2 * rtg + rti][ct]);
          acc2[2 * rtg + rti][ct] = MFMA16(ah[rti], q2l[ct], acc2[2 * rtg + rti][ct]);
          acc2[2 * rtg + rti][ct] = MFMA16(al[rti], q2h[ct], acc2[2 * rtg + rti][ct]);
        }
    }
    __syncthreads();
  }

  // ===== phase C: layer 3 via 2 H2 chunks of 128 cols through the H1 region =====
  f32x4 acc3[4];
#pragma unroll
  for (int rt = 0; rt < 4; ++rt) acc3[rt] = f32x4{0.f, 0.f, 0.f, 0.f};
  const int w3col = 16 * wv + lr;

#pragma unroll
  for (int ch = 0; ch < 2; ++ch) {
    bf16x8 w3h_c, w3l_c;
    {
      int off = ((wv * 8 + 4 * ch) << 9) + lane8;
      w3h_c = *(const bf16x8*)(W3h + off);
      w3l_c = *(const bf16x8*)(W3l + off);
    }
    if (ch) __syncthreads();
    {
      int colC = 16 * wv + lr;
      float bias = b2[128 * ch + colC];
#pragma unroll
      for (int rt = 0; rt < 4; ++rt) {
        float vv[4];
#pragma unroll
        for (int r = 0; r < 4; ++r) vv[r] = fmaxf(acc2[rt][ch][r] + bias, 0.f) * BN_SC;
        unsigned int hp0, lp0, hp1, lp1;
        split_pair(vv[0], vv[1], hp0, lp0);
        split_pair(vv[2], vv[3], hp1, lp1);
        unsigned short hs[4] = {(unsigned short)hp0, (unsigned short)(hp0 >> 16),
                                (unsigned short)hp1, (unsigned short)(hp1 >> 16)};
        unsigned short ls[4] = {(unsigned short)lp0, (unsigned short)(lp0 >> 16),
                                (unsigned short)lp1, (unsigned short)(lp1 >> 16)};
#pragma unroll
        for (int r = 0; r < 4; ++r) {
          int row = 16 * rt + 4 * lg + r;
          int idxs = row * 128 + (((colC >> 3) ^ (row & 7)) * 8) + (colC & 7);
          H2ch[idxs] = hs[r];
          H2cl[idxs] = ls[r];
        }
      }
    }
    __syncthreads();
#pragma unroll
    for (int kt = 0; kt < 4; ++kt) {
      bf16x8 w3h_n, w3l_n;
      if (kt < 3) {
        int off = ((wv * 8 + 4 * ch + kt + 1) << 9) + lane8;
        w3h_n = *(const bf16x8*)(W3h + off);
        w3l_n = *(const bf16x8*)(W3l + off);
      }
#pragma unroll
      for (int rtg = 0; rtg < 2; ++rtg) {
        bf16x8 ah[2], al[2];
#pragma unroll
        for (int rti = 0; rti < 2; ++rti) {
          int arow = 32 * rtg + 16 * rti + lr;
          int aidx = arow * 128 + (((4 * kt + lg) ^ (arow & 7)) * 8);
          ah[rti] = *(const bf16x8*)&H2ch[aidx];
          al[rti] = *(const bf16x8*)&H2cl[aidx];
        }
#pragma unroll
        for (int rti = 0; rti < 2; ++rti) {
          acc3[2 * rtg + rti] = MFMA16(ah[rti], w3h_c, acc3[2 * rtg + rti]);
          acc3[2 * rtg + rti] = MFMA16(ah[rti], w3l_c, acc3[2 * rtg + rti]);
          acc3[2 * rtg + rti] = MFMA16(al[rti], w3h_c, acc3[2 * rtg + rti]);
        }
      }
      w3h_c = w3h_n;
      w3l_c = w3l_n;
    }
  }
  __syncthreads();

  {
    float bias = b3[w3col];
#pragma unroll
    for (int rt = 0; rt < 4; ++rt)
#pragma unroll
      for (int r = 0; r < 4; ++r)
        H3[(16 * rt + 4 * lg + r) * 128 + w3col] = acc3[rt][r] + bias;
  }
  __syncthreads();

  // cosine head: 16 threads per edge
  {
    int i = tid >> 4, j = tid & 15;
    const float* ra = &H3[(2 * i) * 128];
    const float* rb = &H3[(2 * i + 1) * 128];
    float dot = 0.f, s1 = 0.f, s2 = 0.f;
#pragma unroll
    for (int s = 0; s < 8; ++s) {
      float a = ra[j + 16 * s], b = rb[j + 16 * s];
      dot += a * b;
      s1 += a * a;
      s2 += b * b;
    }
#pragma unroll
    for (int m = 8; m >= 1; m >>= 1) {
      dot += __shfl_xor(dot, m);
      s1 += __shfl_xor(s1, m);
      s2 += __shfl_xor(s2, m);
    }
    if (j == 0) {
      float n1 = fmaxf(sqrtf(s1), 1e-8f);
      float n2 = fmaxf(sqrtf(s2), 1e-8f);
      float cosv = dot / (n1 * n2);
      ew[e0 + i] = (cosv + 1.f) * 0.5f;
    }
  }
}

// ======================= Laplacian weights =======================
__global__ __launch_bounds__(256) void k_deg(const int* __restrict__ rowi, const int* __restrict__ colv,
                                             const float* __restrict__ ew, float* __restrict__ deg) {
  int e = blockIdx.x * 256 + threadIdx.x;
  if (e < EE) {
    int r = rowi[e];
    float w = (r == colv[e]) ? 0.f : ew[e];
    atomicAdd(&deg[r], w);
  }
}
__global__ __launch_bounds__(256) void k_dinv(const float* __restrict__ deg, float* __restrict__ dinv) {
  int n = blockIdx.x * 256 + threadIdx.x;
  if (n < NN) { float d = deg[n]; dinv[n] = d > 0.f ? 1.f / sqrtf(d) : 0.f; }
}

// ======================= Cheb propagation: out = alpha*(L@x) + beta*y =======================
template <int DIM>
__global__ __launch_bounds__(256) void k_prop(const float* __restrict__ x, int ldx,
                                              const float* __restrict__ y, int ldy,
                                              float alpha, float beta,
                                              float* __restrict__ outv, int ldo,
                                              const float2* __restrict__ packL,
                                              const int* __restrict__ offs) {
  constexpr int FG = DIM / 4;
  int idx = blockIdx.x * 256 + threadIdx.x;
  int n = idx / FG, g = (idx % FG) * 4;
  if (n >= NN) return;
  float ax = 0.f, ay = 0.f, az = 0.f, aw = 0.f;
  int j1 = offs[n + 1];
  for (int j = offs[n]; j < j1; ++j) {
    float2 p = packL[j];
    float4 v = *(const float4*)(x + (size_t)__float_as_int(p.y) * ldx + g);
    ax += p.x * v.x; ay += p.x * v.y; az += p.x * v.z; aw += p.x * v.w;
  }
  float4 r = make_float4(alpha * ax, alpha * ay, alpha * az, alpha * aw);
  if (beta != 0.f) {
    float4 yv = *(const float4*)(y + (size_t)n * ldy + g);
    r.x += beta * yv.x; r.y += beta * yv.y; r.z += beta * yv.z; r.w += beta * yv.w;
  }
  *(float4*)(outv + (size_t)n * ldo + g) = r;
}

// ======================= cheb combine: relu(sum_k txk @ Wk) -> jk slice =======================
template <int DK>
__global__ __launch_bounds__(512) void k_combine(const float* __restrict__ t0, int ld0,
                                                 const float* __restrict__ t1, int ld1,
                                                 const float* __restrict__ t2, int ld2,
                                                 const float* __restrict__ t3, int ld3,
                                                 const float* __restrict__ W,
                                                 float* __restrict__ outp) {
  int n = blockIdx.x * 8 + (threadIdx.x >> 6);
  int c = threadIdx.x & 63;
  if (n >= NN) return;
  const float* r0 = t0 + (size_t)n * ld0;
  const float* r1 = t1 + (size_t)n * ld1;
  const float* r2 = t2 + (size_t)n * ld2;
  const float* r3 = t3 + (size_t)n * ld3;
  const float* w0 = W;
  const float* w1 = W + DK * 64;
  const float* w2 = W + 2 * DK * 64;
  const float* w3 = W + 3 * DK * 64;
  float acc = 0.f;
#pragma unroll 4
  for (int d = 0; d < DK; ++d) {
    acc += r0[d] * w0[d * 64 + c];
    acc += r1[d] * w1[d * 64 + c];
    acc += r2[d] * w2[d * 64 + c];
    acc += r3[d] * w3[d * 64 + c];
  }
  outp[(size_t)n * 256 + c] = fmaxf(acc, 0.f);
}

// ======================= classifier head =======================
__global__ void k_tr256(const float* __restrict__ A, float* __restrict__ At) {
  int c = blockIdx.x, k = threadIdx.x;
  At[(size_t)k * 256 + c] = A[(size_t)c * 256 + k];
}

__global__ __launch_bounds__(256) void k_mlogit(const float* __restrict__ jk, const float* __restrict__ Wm1t,
                                                const float* __restrict__ bm1, const float* __restrict__ Wm2,
                                                const float* __restrict__ bm2, float* __restrict__ logit1) {
  __shared__ float jks[16 * 256];
  __shared__ float red[16 * 8];
  int tid = threadIdx.x, n0 = blockIdx.x * 16;
  {
    const float4* src = (const float4*)(jk + (size_t)n0 * 256);
    float4* dst = (float4*)jks;
#pragma unroll
    for (int u = 0; u < 4; ++u) dst[tid + 256 * u] = src[tid + 256 * u];
  }
  __syncthreads();
  int c = tid;
  float acc[16];
  float bb = bm1[c];
#pragma unroll
  for (int r = 0; r < 16; ++r) acc[r] = bb;
  for (int k = 0; k < 256; k += 4) {
    float w0 = Wm1t[(size_t)(k + 0) * 256 + c];
    float w1 = Wm1t[(size_t)(k + 1) * 256 + c];
    float w2 = Wm1t[(size_t)(k + 2) * 256 + c];
    float w3 = Wm1t[(size_t)(k + 3) * 256 + c];
#pragma unroll
    for (int r = 0; r < 16; ++r) {
      float4 jv = *(const float4*)&jks[r * 256 + k];
      acc[r] += jv.x * w0 + jv.y * w1 + jv.z * w2 + jv.w * w3;
    }
  }
  float w20 = Wm2[c], w21 = Wm2[256 + c];
  int wid = tid >> 6, lane = tid & 63;
#pragma unroll
  for (int r = 0; r < 16; ++r) {
    float mv = fmaxf(acc[r], 0.f) * BN_SC;
    float v0 = mv * w20, v1 = mv * w21;
#pragma unroll
    for (int m = 32; m >= 1; m >>= 1) {
      v0 += __shfl_xor(v0, m, 64);
      v1 += __shfl_xor(v1, m, 64);
    }
    if (lane == 0) { red[r * 8 + wid] = v0; red[r * 8 + 4 + wid] = v1; }
  }
  __syncthreads();
  if (tid < 32) {
    int r = tid >> 1, cls = tid & 1;
    float s = red[r * 8 + cls * 4] + red[r * 8 + cls * 4 + 1] + red[r * 8 + cls * 4 + 2] + red[r * 8 + cls * 4 + 3];
    logit1[(size_t)(n0 + r) * 2 + cls] = s + bm2[cls];
  }
}

// ======================= bys branch =======================
__global__ __launch_bounds__(256) void k_h0(const float* __restrict__ feat, const float* __restrict__ Wl,
                                            const float* __restrict__ bl, float* __restrict__ h0) {
  int idx = blockIdx.x * 256 + threadIdx.x;
  if (idx >= NN * 16) return;
  int n = idx >> 4, j = idx & 15;
  const float* fr = feat + (size_t)n * 128;
  const float* wr = Wl + (size_t)j * 128;
  float acc = bl[j];
#pragma unroll 8
  for (int d = 0; d < 128; d += 4) {
    float4 f = *(const float4*)(fr + d);
    float4 w = *(const float4*)(wr + d);
    acc += f.x * w.x + f.y * w.y + f.z * w.z + f.w * w.w;
  }
  h0[idx] = acc;
}

__global__ __launch_bounds__(256) void k_bys(const float* __restrict__ hprev, const float* __restrict__ nz,
                                             float* __restrict__ hout,
                                             const float2* __restrict__ packW,
                                             const int* __restrict__ offs) {
  int idx = blockIdx.x * 256 + threadIdx.x;
  int n = idx >> 2, g = (idx & 3) * 4;
  if (n >= NN) return;
  float ax = 0.f, ay = 0.f, az = 0.f, aw = 0.f;
  int j1 = offs[n + 1];
  for (int j = offs[n]; j < j1; ++j) {
    float2 p = packW[j];
    float4 v = *(const float4*)(hprev + ((size_t)__float_as_int(p.y) << 4) + g);
    ax += p.x * v.x; ay += p.x * v.y; az += p.x * v.z; aw += p.x * v.w;
  }
  float4 nv = *(const float4*)(nz + ((size_t)n << 4) + g);
  *(float4*)(hout + ((size_t)n << 4) + g) = make_float4(nv.x + ax, nv.y + ay, nv.z + az, nv.w + aw);
}

// ======================= final: logit2 + softmaxes + max =======================
__global__ __launch_bounds__(256) void k_final(const float* __restrict__ states, const float* __restrict__ Whl,
                                               const float* __restrict__ bhl, const float* __restrict__ logit1,
                                               float* __restrict__ outp) {
  int n = blockIdx.x * 4 + (threadIdx.x >> 6);
  int l = threadIdx.x & 63;
  if (n >= NN) return;
  const float* sf = states + (size_t)n * 400;
  float a0 = 0.f, a1 = 0.f;
  for (int t = l; t < 400; t += 64) {
    float v = sf[t];
    a0 += v * Whl[t];
    a1 += v * Whl[400 + t];
  }
#pragma unroll
  for (int m = 32; m >= 1; m >>= 1) {
    a0 += __shfl_xor(a0, m, 64);
    a1 += __shfl_xor(a1, m, 64);
  }
  if (l == 0) {
    float z0 = 1.f / (1.f + expf(-(a0 + bhl[0])));
    float z1 = 1.f / (1.f + expf(-(a1 + bhl[1])));
    float p20 = 1.f / (1.f + expf(z1 - z0));
    float p21 = 1.f - p20;
    float l10 = logit1[(size_t)n * 2], l11 = logit1[(size_t)n * 2 + 1];
    float p10 = 1.f / (1.f + expf(l11 - l10));
    float p11 = 1.f - p10;
    outp[(size_t)n * 2] = p10;
    outp[(size_t)n * 2 + 1] = p11;
    outp[2 * NN + (size_t)n * 2] = p20;
    outp[2 * NN + (size_t)n * 2 + 1] = p21;
    outp[4 * NN + (size_t)n * 2] = fmaxf(p10, p20);
    outp[4 * NN + (size_t)n * 2 + 1] = fmaxf(p11, p21);
  }
}

// ======================= host =======================
extern "C" void kernel_launch(void* const* d_in, const int* in_sizes, int n_in,
                              void* d_out, int out_size, void* d_ws, size_t ws_size,
                              hipStream_t stream) {
  const float* feat = (const float*)d_in[0];
  const int* ei = (const int*)d_in[1];
  const float* xen = (const float*)d_in[2];
  const float* We1 = (const float*)d_in[3];
  const float* be1 = (const float*)d_in[4];
  const float* We2 = (const float*)d_in[5];
  const float* be2 = (const float*)d_in[6];
  const float* We3 = (const float*)d_in[7];
  const float* be3 = (const float*)d_in[8];
  const float* cw[4] = {(const float*)d_in[9], (const float*)d_in[10], (const float*)d_in[11], (const float*)d_in[12]};
  const float* Wm1 = (const float*)d_in[13];
  const float* bm1 = (const float*)d_in[14];
  const float* Wm2 = (const float*)d_in[15];
  const float* bm2 = (const float*)d_in[16];
  const float* Wl = (const float*)d_in[17];
  const float* bl = (const float*)d_in[18];
  const float* Whl = (const float*)d_in[19];
  const float* bhl = (const float*)d_in[20];
  const float* noise = (const float*)d_in[21];
  float* outp = (float*)d_out;

  char* wp_ = (char*)d_ws;
  auto alloc = [&](size_t bytes) {
    char* p = wp_;
    wp_ += (bytes + 255) & ~(size_t)255;
    return p;
  };
  float* ew = (float*)alloc((size_t)EE * 4);
  float* deg = (float*)alloc((size_t)NN * 4);
  float* dinv = (float*)alloc((size_t)NN * 4);
  int* cnt = (int*)alloc((size_t)NN * 4);
  int* offs = (int*)alloc((size_t)(NN + 1) * 4);
  int* bsum = (int*)alloc((size_t)128 * 4);
  int* eid = (int*)alloc((size_t)EE * 4);
  float2* packW = (float2*)alloc((size_t)EE * 8);
  float2* packL = (float2*)alloc((size_t)EE * 8);
  float* tx1 = (float*)alloc((size_t)NN * 128 * 4);
  float* tx2 = (float*)alloc((size_t)NN * 128 * 4);
  float* tx3 = (float*)alloc((size_t)NN * 128 * 4);
  float* jk = (float*)alloc((size_t)NN * 256 * 4);
  float* logit1 = (float*)alloc((size_t)NN * 2 * 4);
  float* Wm1t = (float*)alloc((size_t)256 * 256 * 4);
  float* h0 = (float*)alloc((size_t)NN * 16 * 4);
  float* states = (float*)alloc((size_t)25 * NN * 16 * 4);
  unsigned short* W1h = (unsigned short*)alloc((size_t)32768 * 2);
  unsigned short* W1l = (unsigned short*)alloc((size_t)32768 * 2);
  unsigned short* W2h = (unsigned short*)alloc((size_t)131072 * 2);
  unsigned short* W2l = (unsigned short*)alloc((size_t)131072 * 2);
  unsigned short* W3h = (unsigned short*)alloc((size_t)32768 * 2);
  unsigned short* W3l = (unsigned short*)alloc((size_t)32768 * 2);

  const int* rowi = ei;
  const int* colv = ei + EE;

  k_wpack<<<128, 256, 0, stream>>>(We1, W1h, W1l, 512, 64);
  k_wpack<<<512, 256, 0, stream>>>(We2, W2h, W2l, 256, 512);
  k_wpack<<<128, 256, 0, stream>>>(We3, W3h, W3l, 128, 256);

  hipMemsetAsync(cnt, 0, (size_t)NN * 4, stream);
  hipMemsetAsync(deg, 0, (size_t)NN * 4, stream);
  k_count<<<1250, 256, 0, stream>>>(colv, cnt);
  k_scan1<<<79, 256, 0, stream>>>(cnt, offs, bsum);
  k_scan2<<<1, 128, 0, stream>>>(bsum);
  k_scan3<<<79, 256, 0, stream>>>(bsum, offs);
  hipMemsetAsync(cnt, 0, (size_t)NN * 4, stream);
  k_fill<<<1250, 256, 0, stream>>>(colv, offs, cnt, eid);
  k_sortl<<<313, 64, 0, stream>>>(offs, eid);

  k_edge_mlp<<<10000, 512, 0, stream>>>(xen, W1h, W1l, be1, W2h, W2l, be2, W3h, W3l, be3, ew);

  k_deg<<<1250, 256, 0, stream>>>(rowi, colv, ew, deg);
  k_dinv<<<79, 256, 0, stream>>>(deg, dinv);
  k_pack<<<1250, 256, 0, stream>>>(eid, rowi, colv, ew, dinv, packW, packL);
  k_tr256<<<256, 256, 0, stream>>>(Wm1, Wm1t);

  // cheb layer 0 (input dim 128): 4 features/thread -> NN*32 threads
  k_prop<128><<<2500, 256, 0, stream>>>(feat, 128, feat, 128, 1.f, 0.f, tx1, 128, packL, offs);
  k_prop<128><<<2500, 256, 0, stream>>>(tx1, 128, feat, 128, 2.f, -1.f, tx2, 128, packL, offs);
  k_prop<128><<<2500, 256, 0, stream>>>(tx2, 128, tx1, 128, 2.f, -1.f, tx3, 128, packL, offs);
  k_combine<128><<<2500, 512, 0, stream>>>(feat, 128, tx1, 128, tx2, 128, tx3, 128, cw[0], jk);
  // cheb layers 1..3 (input dim 64): NN*16 threads
  for (int l = 1; l < 4; ++l) {
    const float* xin = jk + (l - 1) * 64;
    k_prop<64><<<1250, 256, 0, stream>>>(xin, 256, xin, 256, 1.f, 0.f, tx1, 64, packL, offs);
    k_prop<64><<<1250, 256, 0, stream>>>(tx1, 64, xin, 256, 2.f, -1.f, tx2, 64, packL, offs);
    k_prop<64><<<1250, 256, 0, stream>>>(tx2, 64, tx1, 64, 2.f, -1.f, tx3, 64, packL, offs);
    k_combine<64><<<2500, 512, 0, stream>>>(xin, 256, tx1, 64, tx2, 64, tx3, 64, cw[l], jk + l * 64);
  }
  k_mlogit<<<1250, 256, 0, stream>>>(jk, Wm1t, bm1, Wm2, bm2, logit1);

  k_h0<<<1250, 256, 0, stream>>>(feat, Wl, bl, h0);
  const float* hprev = h0;
  for (int s = 0; s < 25; ++s) {
    float* hout = states + (size_t)s * NN * 16;
    k_bys<<<313, 256, 0, stream>>>(hprev, noise + (size_t)s * NN * 16, hout, packW, offs);
    hprev = hout;
  }
  k_final<<<5000, 256, 0, stream>>>(states, Whl, bhl, logit1, outp);
}

// Round 13
// 1805.708 us; speedup vs baseline: 1.1114x; 1.1114x over previous
//
#include <hip/hip_runtime.h>
#include <math.h>

#define NN 20000
#define EE 320000
#define BN_SC 0.9999950000374997f

typedef __attribute__((ext_vector_type(8))) short bf16x8;
typedef __attribute__((ext_vector_type(4))) float f32x4;

__device__ __forceinline__ unsigned short f2b(float x) {
  unsigned int u = __builtin_bit_cast(unsigned int, x);
  u += 0x7FFFu + ((u >> 16) & 1u);
  return (unsigned short)(u >> 16);
}
__device__ __forceinline__ void split2(float x, unsigned short& h, unsigned short& l) {
  h = f2b(x);
  float hf = __builtin_bit_cast(float, (unsigned int)h << 16);
  l = f2b(x - hf);
}

// ======================= weight split + MFMA-fragment repack =======================
// Packed layout: per 16-col x 32-k tile (512 ushorts = 1KB), element order
// [lane = lg*16+lr][e 0..7] -> value Worig[col = ct*16+lr][k = kt*32+lg*8+e].
// A wave's B-fragment load is base+tile*512+lane*8: one contiguous 1KB block.
__global__ __launch_bounds__(256) void k_wpack(const float* __restrict__ W, unsigned short* __restrict__ Wh,
                                               unsigned short* __restrict__ Wl, int C, int K) {
  int i = blockIdx.x * 256 + threadIdx.x;
  if (i >= C * K) return;
  int e = i & 7;
  int lane = (i >> 3) & 63;
  int tile = i >> 9;
  int KT = K >> 5;
  int kt = tile % KT, ct = tile / KT;
  int lr = lane & 15, lg = lane >> 4;
  int col = ct * 16 + lr;
  int k = kt * 32 + lg * 8 + e;
  unsigned short h, l;
  split2(W[(size_t)col * K + k], h, l);
  Wh[i] = h;
  Wl[i] = l;
}

// ======================= CSR build (by destination col) =======================
__global__ __launch_bounds__(256) void k_count(const int* __restrict__ colv, int* __restrict__ cnt) {
  int e = blockIdx.x * 256 + threadIdx.x;
  if (e < EE) atomicAdd(&cnt[colv[e]], 1);
}

// hierarchical scan
__global__ __launch_bounds__(256) void k_scan1(const int* __restrict__ cnt, int* __restrict__ offs,
                                               int* __restrict__ bsum) {
  __shared__ int sb[256];
  int t = threadIdx.x, i = blockIdx.x * 256 + t;
  int v = (i < NN) ? cnt[i] : 0;
  sb[t] = v;
  __syncthreads();
  for (int off = 1; off < 256; off <<= 1) {
    int x = (t >= off) ? sb[t - off] : 0;
    __syncthreads();
    sb[t] += x;
    __syncthreads();
  }
  if (i < NN) offs[i + 1] = sb[t];  // block-inclusive
  if (t == 255) bsum[blockIdx.x] = sb[255];
}
__global__ __launch_bounds__(128) void k_scan2(int* __restrict__ bsum) {
  __shared__ int sb[128];
  int t = threadIdx.x;
  int v = (t < 79) ? bsum[t] : 0;
  sb[t] = v;
  __syncthreads();
  for (int off = 1; off < 128; off <<= 1) {
    int x = (t >= off) ? sb[t - off] : 0;
    __syncthreads();
    sb[t] += x;
    __syncthreads();
  }
  if (t < 79) bsum[t] = sb[t] - v;  // exclusive
}
__global__ __launch_bounds__(256) void k_scan3(const int* __restrict__ bsum, int* __restrict__ offs) {
  int i = blockIdx.x * 256 + threadIdx.x;
  if (i == 0) offs[0] = 0;
  if (i < NN) offs[i + 1] += bsum[blockIdx.x];
}

__global__ __launch_bounds__(256) void k_fill(const int* __restrict__ colv, const int* __restrict__ offs,
                                              int* __restrict__ cur, int* __restrict__ eid) {
  int e = blockIdx.x * 256 + threadIdx.x;
  if (e < EE) {
    int d = colv[e];
    int p = atomicAdd(&cur[d], 1);
    eid[offs[d] + p] = e;
  }
}

// deterministic per-node edge order; sort in LDS
__global__ __launch_bounds__(64) void k_sortl(const int* __restrict__ offs, int* __restrict__ eid) {
  __shared__ int buf[64 * 97];  // 97 stride: avoid bank conflict
  int n = blockIdx.x * 64 + threadIdx.x;
  if (n >= NN) return;
  int j0 = offs[n], j1 = offs[n + 1], d = j1 - j0;
  int* b = &buf[threadIdx.x * 97];
  if (d <= 96) {
    for (int i = 0; i < d; ++i) b[i] = eid[j0 + i];
    for (int i = 1; i < d; ++i) {
      int v = b[i];
      int j = i - 1;
      while (j >= 0 && b[j] > v) { b[j + 1] = b[j]; --j; }
      b[j + 1] = v;
    }
    for (int i = 0; i < d; ++i) eid[j0 + i] = b[i];
  } else {
    for (int i = j0 + 1; i < j1; ++i) {
      int v = eid[i];
      int j = i - 1;
      while (j >= j0 && eid[j] > v) { eid[j + 1] = eid[j]; --j; }
      eid[j + 1] = v;
    }
  }
}

// pack (weight, src_row) per CSR slot; lapw computed inline
__global__ __launch_bounds__(256) void k_pack(const int* __restrict__ eid, const int* __restrict__ rowi,
                                              const int* __restrict__ colv,
                                              const float* __restrict__ ew, const float* __restrict__ dinv,
                                              float2* __restrict__ packW, float2* __restrict__ packL) {
  int j = blockIdx.x * 256 + threadIdx.x;
  if (j < EE) {
    int e = eid[j];
    int r = rowi[e], c = colv[e];
    float rw = __int_as_float(r);
    float w = (r == c) ? 0.f : ew[e];
    packW[j] = make_float2(ew[e], rw);
    packL[j] = make_float2(-dinv[r] * w * dinv[c], rw);
  }
}

// ======================= fused edge MLP (MFMA split-bf16) + cosine =======================
// EXACT R12 version (694us, 46% occupancy, VGPR 64). R13's cvt_pk variant grew arch
// VGPR 64->72, broke the 128-reg (arch+AGPR) residency cliff -> 1 block/CU -> 965us.
// This kernel sits ON the cliff: any register growth halves occupancy.
#define MFMA16(a, b, c) __builtin_amdgcn_mfma_f32_16x16x32_bf16(a, b, c, 0, 0, 0)

__global__ __launch_bounds__(512, 2) void k_edge_mlp(
    const float* __restrict__ X,
    const unsigned short* __restrict__ W1h, const unsigned short* __restrict__ W1l, const float* __restrict__ b1,
    const unsigned short* __restrict__ W2h, const unsigned short* __restrict__ W2l, const float* __restrict__ b2,
    const unsigned short* __restrict__ W3h, const unsigned short* __restrict__ W3l, const float* __restrict__ b3,
    float* __restrict__ ew) {
  __shared__ __align__(16) unsigned short POOL[24576];  // 48 KB
  unsigned short* Xh = POOL;          // [64][64]
  unsigned short* Xl = POOL + 4096;   // [64][64]
  unsigned short* H2ch = POOL + 8192;   // phase C: [64][128], aliases H1 bufs
  unsigned short* H2cl = POOL + 16384;  // phase C: [64][128]
  float* H3 = (float*)(POOL + 8192);    // tail: [64][128] f32 = 32KB

  const int tid = threadIdx.x;
  const int wv = tid >> 6;
  const int lane = tid & 63;
  const int lr = lane & 15;
  const int lg = lane >> 4;
  const int e0 = blockIdx.x * 32;
  const int lane8 = lane << 3;

  const int rt1 = wv & 3;
  const int ch1 = wv >> 2;

  // ---- stage X[64 rows][64 cols] as split bf16, swizzled (8 threads/row) ----
  {
    int row = tid >> 3, eighth = tid & 7;
    const float* src = X + (size_t)(e0 + (row >> 1)) * 128 + (row & 1) * 64 + eighth * 8;
    float4 a = ((const float4*)src)[0];
    float4 b = ((const float4*)src)[1];
    float vals[8] = {a.x, a.y, a.z, a.w, b.x, b.y, b.z, b.w};
    unsigned short hs[8], ls[8];
#pragma unroll
    for (int j = 0; j < 8; ++j) split2(vals[j], hs[j], ls[j]);
    int chunk = eighth ^ (row & 7);
    int idxs = row * 64 + chunk * 8;
#pragma unroll
    for (int j = 0; j < 8; ++j) { Xh[idxs + j] = hs[j]; Xl[idxs + j] = ls[j]; }
  }
  __syncthreads();

  // layer-1 compute for 64-col chunk c into H1 buffer b.
  auto l1_compute = [&](int c, int b) {
    unsigned short* H1h = POOL + 8192 + b * 8192;
    unsigned short* H1l = POOL + 12288 + b * 8192;
    f32x4 acc1[2];
#pragma unroll
    for (int cti = 0; cti < 2; ++cti) acc1[cti] = f32x4{0.f, 0.f, 0.f, 0.f};
#pragma unroll
    for (int kt = 0; kt < 2; ++kt) {
      int arow = 16 * rt1 + lr;
      int aidx = arow * 64 + ((4 * kt + lg) ^ (arow & 7)) * 8;
      bf16x8 ah = *(const bf16x8*)&Xh[aidx];
      bf16x8 al = *(const bf16x8*)&Xl[aidx];
#pragma unroll
      for (int cti = 0; cti < 2; ++cti) {
        int off = (((4 * c + 2 * ch1 + cti) * 2 + kt) << 9) + lane8;
        bf16x8 bh = *(const bf16x8*)(W1h + off);
        bf16x8 bl = *(const bf16x8*)(W1l + off);
        acc1[cti] = MFMA16(ah, bh, acc1[cti]);
        acc1[cti] = MFMA16(ah, bl, acc1[cti]);
        acc1[cti] = MFMA16(al, bh, acc1[cti]);
      }
    }
#pragma unroll
    for (int cti = 0; cti < 2; ++cti) {
      int colL = 16 * (2 * ch1 + cti) + lr;
      float bias = b1[64 * c + colL];
#pragma unroll
      for (int r = 0; r < 4; ++r) {
        float v = fmaxf(acc1[cti][r] + bias, 0.f) * BN_SC;
        unsigned short hs, ls;
        split2(v, hs, ls);
        int row = 16 * rt1 + 4 * lg + r;
        int idxs = row * 64 + (((colL >> 3) ^ (row & 7)) * 8) + (colL & 7);
        H1h[idxs] = hs;
        H1l[idxs] = ls;
      }
    }
  };

  f32x4 acc2[4][2];
#pragma unroll
  for (int rt = 0; rt < 4; ++rt)
#pragma unroll
    for (int ct = 0; ct < 2; ++ct) acc2[rt][ct] = f32x4{0.f, 0.f, 0.f, 0.f};

  l1_compute(0, 0);
  __syncthreads();

  // ===== pipelined main loop: 8 chunks of 64 H1-cols, ONE barrier each =====
  for (int kc = 0; kc < 8; ++kc) {
    int cur = kc & 1;
    unsigned short* H1h = POOL + 8192 + cur * 8192;
    unsigned short* H1l = POOL + 12288 + cur * 8192;
    bf16x8 p2h[2], p2l[2];
    {
#pragma unroll
      for (int ct = 0; ct < 2; ++ct) {
        int off = (((8 * ct + wv) * 16 + 2 * kc) << 9) + lane8;
        p2h[ct] = *(const bf16x8*)(W2h + off);
        p2l[ct] = *(const bf16x8*)(W2l + off);
      }
    }
    if (kc < 7) l1_compute(kc + 1, cur ^ 1);
    bf16x8 q2h[2], q2l[2];
    {
#pragma unroll
      for (int ct = 0; ct < 2; ++ct) {
        int off = (((8 * ct + wv) * 16 + 2 * kc + 1) << 9) + lane8;
        q2h[ct] = *(const bf16x8*)(W2h + off);
        q2l[ct] = *(const bf16x8*)(W2l + off);
      }
    }
#pragma unroll
    for (int rtg = 0; rtg < 2; ++rtg) {
      bf16x8 ah[2], al[2];
#pragma unroll
      for (int rti = 0; rti < 2; ++rti) {
        int arow = 32 * rtg + 16 * rti + lr;
        int aidx = arow * 64 + (lg ^ (arow & 7)) * 8;
        ah[rti] = *(const bf16x8*)&H1h[aidx];
        al[rti] = *(const bf16x8*)&H1l[aidx];
      }
#pragma unroll
      for (int ct = 0; ct < 2; ++ct)
#pragma unroll
        for (int rti = 0; rti < 2; ++rti) {
          acc2[2 * rtg + rti][ct] = MFMA16(ah[rti], p2h[ct], acc2[2 * rtg + rti][ct]);
          acc2[2 * rtg + rti][ct] = MFMA16(ah[rti], p2l[ct], acc2[2 * rtg + rti][ct]);
          acc2[2 * rtg + rti][ct] = MFMA16(al[rti], p2h[ct], acc2[2 * rtg + rti][ct]);
        }
    }
#pragma unroll
    for (int rtg = 0; rtg < 2; ++rtg) {
      bf16x8 ah[2], al[2];
#pragma unroll
      for (int rti = 0; rti < 2; ++rti) {
        int arow = 32 * rtg + 16 * rti + lr;
        int aidx = arow * 64 + ((4 + lg) ^ (arow & 7)) * 8;
        ah[rti] = *(const bf16x8*)&H1h[aidx];
        al[rti] = *(const bf16x8*)&H1l[aidx];
      }
#pragma unroll
      for (int ct = 0; ct < 2; ++ct)
#pragma unroll
        for (int rti = 0; rti < 2; ++rti) {
          acc2[2 * rtg + rti][ct] = MFMA16(ah[rti], q2h[ct], acc2[2 * rtg + rti][ct]);
          acc2[2 * rtg + rti][ct] = MFMA16(ah[rti], q2l[ct], acc2[2 * rtg + rti][ct]);
          acc2[2 * rtg + rti][ct] = MFMA16(al[rti], q2h[ct], acc2[2 * rtg + rti][ct]);
        }
    }
    __syncthreads();
  }

  // ===== phase C: layer 3 via 2 H2 chunks of 128 cols through the H1 region =====
  f32x4 acc3[4];
#pragma unroll
  for (int rt = 0; rt < 4; ++rt) acc3[rt] = f32x4{0.f, 0.f, 0.f, 0.f};
  const int w3col = 16 * wv + lr;

#pragma unroll
  for (int ch = 0; ch < 2; ++ch) {
    bf16x8 w3h_c, w3l_c;
    {
      int off = ((wv * 8 + 4 * ch) << 9) + lane8;
      w3h_c = *(const bf16x8*)(W3h + off);
      w3l_c = *(const bf16x8*)(W3l + off);
    }
    if (ch) __syncthreads();
    {
      int colC = 16 * wv + lr;
      float bias = b2[128 * ch + colC];
#pragma unroll
      for (int rt = 0; rt < 4; ++rt) {
#pragma unroll
        for (int r = 0; r < 4; ++r) {
          float v = fmaxf(acc2[rt][ch][r] + bias, 0.f) * BN_SC;
          unsigned short hs, ls;
          split2(v, hs, ls);
          int row = 16 * rt + 4 * lg + r;
          int idxs = row * 128 + (((colC >> 3) ^ (row & 7)) * 8) + (colC & 7);
          H2ch[idxs] = hs;
          H2cl[idxs] = ls;
        }
      }
    }
    __syncthreads();
#pragma unroll
    for (int kt = 0; kt < 4; ++kt) {
      bf16x8 w3h_n, w3l_n;
      if (kt < 3) {
        int off = ((wv * 8 + 4 * ch + kt + 1) << 9) + lane8;
        w3h_n = *(const bf16x8*)(W3h + off);
        w3l_n = *(const bf16x8*)(W3l + off);
      }
#pragma unroll
      for (int rtg = 0; rtg < 2; ++rtg) {
        bf16x8 ah[2], al[2];
#pragma unroll
        for (int rti = 0; rti < 2; ++rti) {
          int arow = 32 * rtg + 16 * rti + lr;
          int aidx = arow * 128 + (((4 * kt + lg) ^ (arow & 7)) * 8);
          ah[rti] = *(const bf16x8*)&H2ch[aidx];
          al[rti] = *(const bf16x8*)&H2cl[aidx];
        }
#pragma unroll
        for (int rti = 0; rti < 2; ++rti) {
          acc3[2 * rtg + rti] = MFMA16(ah[rti], w3h_c, acc3[2 * rtg + rti]);
          acc3[2 * rtg + rti] = MFMA16(ah[rti], w3l_c, acc3[2 * rtg + rti]);
          acc3[2 * rtg + rti] = MFMA16(al[rti], w3h_c, acc3[2 * rtg + rti]);
        }
      }
      w3h_c = w3h_n;
      w3l_c = w3l_n;
    }
  }
  __syncthreads();

  {
    float bias = b3[w3col];
#pragma unroll
    for (int rt = 0; rt < 4; ++rt)
#pragma unroll
      for (int r = 0; r < 4; ++r)
        H3[(16 * rt + 4 * lg + r) * 128 + w3col] = acc3[rt][r] + bias;
  }
  __syncthreads();

  // cosine head: 16 threads per edge
  {
    int i = tid >> 4, j = tid & 15;
    const float* ra = &H3[(2 * i) * 128];
    const float* rb = &H3[(2 * i + 1) * 128];
    float dot = 0.f, s1 = 0.f, s2 = 0.f;
#pragma unroll
    for (int s = 0; s < 8; ++s) {
      float a = ra[j + 16 * s], b = rb[j + 16 * s];
      dot += a * b;
      s1 += a * a;
      s2 += b * b;
    }
#pragma unroll
    for (int m = 8; m >= 1; m >>= 1) {
      dot += __shfl_xor(dot, m);
      s1 += __shfl_xor(s1, m);
      s2 += __shfl_xor(s2, m);
    }
    if (j == 0) {
      float n1 = fmaxf(sqrtf(s1), 1e-8f);
      float n2 = fmaxf(sqrtf(s2), 1e-8f);
      float cosv = dot / (n1 * n2);
      ew[e0 + i] = (cosv + 1.f) * 0.5f;
    }
  }
}

// ======================= Laplacian weights =======================
__global__ __launch_bounds__(256) void k_deg(const int* __restrict__ rowi, const int* __restrict__ colv,
                                             const float* __restrict__ ew, float* __restrict__ deg) {
  int e = blockIdx.x * 256 + threadIdx.x;
  if (e < EE) {
    int r = rowi[e];
    float w = (r == colv[e]) ? 0.f : ew[e];
    atomicAdd(&deg[r], w);
  }
}
__global__ __launch_bounds__(256) void k_dinv(const float* __restrict__ deg, float* __restrict__ dinv) {
  int n = blockIdx.x * 256 + threadIdx.x;
  if (n < NN) { float d = deg[n]; dinv[n] = d > 0.f ? 1.f / sqrtf(d) : 0.f; }
}

// ======================= Cheb propagation: out = alpha*(L@x) + beta*y =======================
template <int DIM>
__global__ __launch_bounds__(256) void k_prop(const float* __restrict__ x, int ldx,
                                              const float* __restrict__ y, int ldy,
                                              float alpha, float beta,
                                              float* __restrict__ outv, int ldo,
                                              const float2* __restrict__ packL,
                                              const int* __restrict__ offs) {
  constexpr int FG = DIM / 4;
  int idx = blockIdx.x * 256 + threadIdx.x;
  int n = idx / FG, g = (idx % FG) * 4;
  if (n >= NN) return;
  float ax = 0.f, ay = 0.f, az = 0.f, aw = 0.f;
  int j1 = offs[n + 1];
  for (int j = offs[n]; j < j1; ++j) {
    float2 p = packL[j];
    float4 v = *(const float4*)(x + (size_t)__float_as_int(p.y) * ldx + g);
    ax += p.x * v.x; ay += p.x * v.y; az += p.x * v.z; aw += p.x * v.w;
  }
  float4 r = make_float4(alpha * ax, alpha * ay, alpha * az, alpha * aw);
  if (beta != 0.f) {
    float4 yv = *(const float4*)(y + (size_t)n * ldy + g);
    r.x += beta * yv.x; r.y += beta * yv.y; r.z += beta * yv.z; r.w += beta * yv.w;
  }
  *(float4*)(outv + (size_t)n * ldo + g) = r;
}

// ======================= cheb combine: relu(sum_k txk @ Wk) -> jk slice =======================
template <int DK>
__global__ __launch_bounds__(512) void k_combine(const float* __restrict__ t0, int ld0,
                                                 const float* __restrict__ t1, int ld1,
                                                 const float* __restrict__ t2, int ld2,
                                                 const float* __restrict__ t3, int ld3,
                                                 const float* __restrict__ W,
                                                 float* __restrict__ outp) {
  int n = blockIdx.x * 8 + (threadIdx.x >> 6);
  int c = threadIdx.x & 63;
  if (n >= NN) return;
  const float* r0 = t0 + (size_t)n * ld0;
  const float* r1 = t1 + (size_t)n * ld1;
  const float* r2 = t2 + (size_t)n * ld2;
  const float* r3 = t3 + (size_t)n * ld3;
  const float* w0 = W;
  const float* w1 = W + DK * 64;
  const float* w2 = W + 2 * DK * 64;
  const float* w3 = W + 3 * DK * 64;
  float acc = 0.f;
#pragma unroll 4
  for (int d = 0; d < DK; ++d) {
    acc += r0[d] * w0[d * 64 + c];
    acc += r1[d] * w1[d * 64 + c];
    acc += r2[d] * w2[d * 64 + c];
    acc += r3[d] * w3[d * 64 + c];
  }
  outp[(size_t)n * 256 + c] = fmaxf(acc, 0.f);
}

// ======================= classifier head =======================
__global__ void k_tr256(const float* __restrict__ A, float* __restrict__ At) {
  int c = blockIdx.x, k = threadIdx.x;
  At[(size_t)k * 256 + c] = A[(size_t)c * 256 + k];
}

__global__ __launch_bounds__(256) void k_mlogit(const float* __restrict__ jk, const float* __restrict__ Wm1t,
                                                const float* __restrict__ bm1, const float* __restrict__ Wm2,
                                                const float* __restrict__ bm2, float* __restrict__ logit1) {
  __shared__ float jks[16 * 256];
  __shared__ float red[16 * 8];
  int tid = threadIdx.x, n0 = blockIdx.x * 16;
  {
    const float4* src = (const float4*)(jk + (size_t)n0 * 256);
    float4* dst = (float4*)jks;
#pragma unroll
    for (int u = 0; u < 4; ++u) dst[tid + 256 * u] = src[tid + 256 * u];
  }
  __syncthreads();
  int c = tid;
  float acc[16];
  float bb = bm1[c];
#pragma unroll
  for (int r = 0; r < 16; ++r) acc[r] = bb;
  for (int k = 0; k < 256; k += 4) {
    float w0 = Wm1t[(size_t)(k + 0) * 256 + c];
    float w1 = Wm1t[(size_t)(k + 1) * 256 + c];
    float w2 = Wm1t[(size_t)(k + 2) * 256 + c];
    float w3 = Wm1t[(size_t)(k + 3) * 256 + c];
#pragma unroll
    for (int r = 0; r < 16; ++r) {
      float4 jv = *(const float4*)&jks[r * 256 + k];
      acc[r] += jv.x * w0 + jv.y * w1 + jv.z * w2 + jv.w * w3;
    }
  }
  float w20 = Wm2[c], w21 = Wm2[256 + c];
  int wid = tid >> 6, lane = tid & 63;
#pragma unroll
  for (int r = 0; r < 16; ++r) {
    float mv = fmaxf(acc[r], 0.f) * BN_SC;
    float v0 = mv * w20, v1 = mv * w21;
#pragma unroll
    for (int m = 32; m >= 1; m >>= 1) {
      v0 += __shfl_xor(v0, m, 64);
      v1 += __shfl_xor(v1, m, 64);
    }
    if (lane == 0) { red[r * 8 + wid] = v0; red[r * 8 + 4 + wid] = v1; }
  }
  __syncthreads();
  if (tid < 32) {
    int r = tid >> 1, cls = tid & 1;
    float s = red[r * 8 + cls * 4] + red[r * 8 + cls * 4 + 1] + red[r * 8 + cls * 4 + 2] + red[r * 8 + cls * 4 + 3];
    logit1[(size_t)(n0 + r) * 2 + cls] = s + bm2[cls];
  }
}

// ======================= bys branch =======================
__global__ __launch_bounds__(256) void k_h0(const float* __restrict__ feat, const float* __restrict__ Wl,
                                            const float* __restrict__ bl, float* __restrict__ h0) {
  int idx = blockIdx.x * 256 + threadIdx.x;
  if (idx >= NN * 16) return;
  int n = idx >> 4, j = idx & 15;
  const float* fr = feat + (size_t)n * 128;
  const float* wr = Wl + (size_t)j * 128;
  float acc = bl[j];
#pragma unroll 8
  for (int d = 0; d < 128; d += 4) {
    float4 f = *(const float4*)(fr + d);
    float4 w = *(const float4*)(wr + d);
    acc += f.x * w.x + f.y * w.y + f.z * w.z + f.w * w.w;
  }
  h0[idx] = acc;
}

__global__ __launch_bounds__(256) void k_bys(const float* __restrict__ hprev, const float* __restrict__ nz,
                                             float* __restrict__ hout,
                                             const float2* __restrict__ packW,
                                             const int* __restrict__ offs) {
  int idx = blockIdx.x * 256 + threadIdx.x;
  int n = idx >> 2, g = (idx & 3) * 4;
  if (n >= NN) return;
  float ax = 0.f, ay = 0.f, az = 0.f, aw = 0.f;
  int j1 = offs[n + 1];
  for (int j = offs[n]; j < j1; ++j) {
    float2 p = packW[j];
    float4 v = *(const float4*)(hprev + ((size_t)__float_as_int(p.y) << 4) + g);
    ax += p.x * v.x; ay += p.x * v.y; az += p.x * v.z; aw += p.x * v.w;
  }
  float4 nv = *(const float4*)(nz + ((size_t)n << 4) + g);
  *(float4*)(hout + ((size_t)n << 4) + g) = make_float4(nv.x + ax, nv.y + ay, nv.z + az, nv.w + aw);
}

// ======================= final: logit2 + softmaxes + max =======================
__global__ __launch_bounds__(256) void k_final(const float* __restrict__ states, const float* __restrict__ Whl,
                                               const float* __restrict__ bhl, const float* __restrict__ logit1,
                                               float* __restrict__ outp) {
  int n = blockIdx.x * 4 + (threadIdx.x >> 6);
  int l = threadIdx.x & 63;
  if (n >= NN) return;
  const float* sf = states + (size_t)n * 400;
  float a0 = 0.f, a1 = 0.f;
  for (int t = l; t < 400; t += 64) {
    float v = sf[t];
    a0 += v * Whl[t];
    a1 += v * Whl[400 + t];
  }
#pragma unroll
  for (int m = 32; m >= 1; m >>= 1) {
    a0 += __shfl_xor(a0, m, 64);
    a1 += __shfl_xor(a1, m, 64);
  }
  if (l == 0) {
    float z0 = 1.f / (1.f + expf(-(a0 + bhl[0])));
    float z1 = 1.f / (1.f + expf(-(a1 + bhl[1])));
    float p20 = 1.f / (1.f + expf(z1 - z0));
    float p21 = 1.f - p20;
    float l10 = logit1[(size_t)n * 2], l11 = logit1[(size_t)n * 2 + 1];
    float p10 = 1.f / (1.f + expf(l11 - l10));
    float p11 = 1.f - p10;
    outp[(size_t)n * 2] = p10;
    outp[(size_t)n * 2 + 1] = p11;
    outp[2 * NN + (size_t)n * 2] = p20;
    outp[2 * NN + (size_t)n * 2 + 1] = p21;
    outp[4 * NN + (size_t)n * 2] = fmaxf(p10, p20);
    outp[4 * NN + (size_t)n * 2 + 1] = fmaxf(p11, p21);
  }
}

// ======================= host =======================
extern "C" void kernel_launch(void* const* d_in, const int* in_sizes, int n_in,
                              void* d_out, int out_size, void* d_ws, size_t ws_size,
                              hipStream_t stream) {
  const float* feat = (const float*)d_in[0];
  const int* ei = (const int*)d_in[1];
  const float* xen = (const float*)d_in[2];
  const float* We1 = (const float*)d_in[3];
  const float* be1 = (const float*)d_in[4];
  const float* We2 = (const float*)d_in[5];
  const float* be2 = (const float*)d_in[6];
  const float* We3 = (const float*)d_in[7];
  const float* be3 = (const float*)d_in[8];
  const float* cw[4] = {(const float*)d_in[9], (const float*)d_in[10], (const float*)d_in[11], (const float*)d_in[12]};
  const float* Wm1 = (const float*)d_in[13];
  const float* bm1 = (const float*)d_in[14];
  const float* Wm2 = (const float*)d_in[15];
  const float* bm2 = (const float*)d_in[16];
  const float* Wl = (const float*)d_in[17];
  const float* bl = (const float*)d_in[18];
  const float* Whl = (const float*)d_in[19];
  const float* bhl = (const float*)d_in[20];
  const float* noise = (const float*)d_in[21];
  float* outp = (float*)d_out;

  char* wp_ = (char*)d_ws;
  auto alloc = [&](size_t bytes) {
    char* p = wp_;
    wp_ += (bytes + 255) & ~(size_t)255;
    return p;
  };
  float* ew = (float*)alloc((size_t)EE * 4);
  float* deg = (float*)alloc((size_t)NN * 4);
  float* dinv = (float*)alloc((size_t)NN * 4);
  int* cnt = (int*)alloc((size_t)NN * 4);
  int* offs = (int*)alloc((size_t)(NN + 1) * 4);
  int* bsum = (int*)alloc((size_t)128 * 4);
  int* eid = (int*)alloc((size_t)EE * 4);
  float2* packW = (float2*)alloc((size_t)EE * 8);
  float2* packL = (float2*)alloc((size_t)EE * 8);
  float* tx1 = (float*)alloc((size_t)NN * 128 * 4);
  float* tx2 = (float*)alloc((size_t)NN * 128 * 4);
  float* tx3 = (float*)alloc((size_t)NN * 128 * 4);
  float* jk = (float*)alloc((size_t)NN * 256 * 4);
  float* logit1 = (float*)alloc((size_t)NN * 2 * 4);
  float* Wm1t = (float*)alloc((size_t)256 * 256 * 4);
  float* h0 = (float*)alloc((size_t)NN * 16 * 4);
  float* states = (float*)alloc((size_t)25 * NN * 16 * 4);
  unsigned short* W1h = (unsigned short*)alloc((size_t)32768 * 2);
  unsigned short* W1l = (unsigned short*)alloc((size_t)32768 * 2);
  unsigned short* W2h = (unsigned short*)alloc((size_t)131072 * 2);
  unsigned short* W2l = (unsigned short*)alloc((size_t)131072 * 2);
  unsigned short* W3h = (unsigned short*)alloc((size_t)32768 * 2);
  unsigned short* W3l = (unsigned short*)alloc((size_t)32768 * 2);

  const int* rowi = ei;
  const int* colv = ei + EE;

  k_wpack<<<128, 256, 0, stream>>>(We1, W1h, W1l, 512, 64);
  k_wpack<<<512, 256, 0, stream>>>(We2, W2h, W2l, 256, 512);
  k_wpack<<<128, 256, 0, stream>>>(We3, W3h, W3l, 128, 256);

  hipMemsetAsync(cnt, 0, (size_t)NN * 4, stream);
  hipMemsetAsync(deg, 0, (size_t)NN * 4, stream);
  k_count<<<1250, 256, 0, stream>>>(colv, cnt);
  k_scan1<<<79, 256, 0, stream>>>(cnt, offs, bsum);
  k_scan2<<<1, 128, 0, stream>>>(bsum);
  k_scan3<<<79, 256, 0, stream>>>(bsum, offs);
  hipMemsetAsync(cnt, 0, (size_t)NN * 4, stream);
  k_fill<<<1250, 256, 0, stream>>>(colv, offs, cnt, eid);
  k_sortl<<<313, 64, 0, stream>>>(offs, eid);

  k_edge_mlp<<<10000, 512, 0, stream>>>(xen, W1h, W1l, be1, W2h, W2l, be2, W3h, W3l, be3, ew);

  k_deg<<<1250, 256, 0, stream>>>(rowi, colv, ew, deg);
  k_dinv<<<79, 256, 0, stream>>>(deg, dinv);
  k_pack<<<1250, 256, 0, stream>>>(eid, rowi, colv, ew, dinv, packW, packL);
  k_tr256<<<256, 256, 0, stream>>>(Wm1, Wm1t);

  // cheb layer 0 (input dim 128): 4 features/thread -> NN*32 threads
  k_prop<128><<<2500, 256, 0, stream>>>(feat, 128, feat, 128, 1.f, 0.f, tx1, 128, packL, offs);
  k_prop<128><<<2500, 256, 0, stream>>>(tx1, 128, feat, 128, 2.f, -1.f, tx2, 128, packL, offs);
  k_prop<128><<<2500, 256, 0, stream>>>(tx2, 128, tx1, 128, 2.f, -1.f, tx3, 128, packL, offs);
  k_combine<128><<<2500, 512, 0, stream>>>(feat, 128, tx1, 128, tx2, 128, tx3, 128, cw[0], jk);
  // cheb layers 1..3 (input dim 64): NN*16 threads
  for (int l = 1; l < 4; ++l) {
    const float* xin = jk + (l - 1) * 64;
    k_prop<64><<<1250, 256, 0, stream>>>(xin, 256, xin, 256, 1.f, 0.f, tx1, 64, packL, offs);
    k_prop<64><<<1250, 256, 0, stream>>>(tx1, 64, xin, 256, 2.f, -1.f, tx2, 64, packL, offs);
    k_prop<64><<<1250, 256, 0, stream>>>(tx2, 64, tx1, 64, 2.f, -1.f, tx3, 64, packL, offs);
    k_combine<64><<<2500, 512, 0, stream>>>(xin, 256, tx1, 64, tx2, 64, tx3, 64, cw[l], jk + l * 64);
  }
  k_mlogit<<<1250, 256, 0, stream>>>(jk, Wm1t, bm1, Wm2, bm2, logit1);

  k_h0<<<1250, 256, 0, stream>>>(feat, Wl, bl, h0);
  const float* hprev = h0;
  for (int s = 0; s < 25; ++s) {
    float* hout = states + (size_t)s * NN * 16;
    k_bys<<<313, 256, 0, stream>>>(hprev, noise + (size_t)s * NN * 16, hout, packW, offs);
    hprev = hout;
  }
  k_final<<<5000, 256, 0, stream>>>(states, Whl, bhl, logit1, outp);
}